// Round 19
// baseline (81.072 us; speedup 1.0000x reference)
//
#include <hip/hip_runtime.h>
#include <stdint.h>
#include <math.h>

#define CDIM 512
#define NHEAD 8
#define HD 64
#define HWD 1024
#define BATCH 8
#define NGRP 32
#define CPG 16
#define EPSV 1e-5f
// q scale folded with log2(e): attn softmax uses raw v_exp_f32 (2^x) directly
#define QSC_L2E (0.125f * 1.44269504088896340736f)

typedef __bf16 bf16x8 __attribute__((ext_vector_type(8)));
typedef float f32x4 __attribute__((ext_vector_type(4)));

static __device__ __forceinline__ unsigned short f2bf(float x){
  union { float f; unsigned u; } v; v.f = x;
  unsigned r = v.u + 0x7fffu + ((v.u >> 16) & 1u);
  return (unsigned short)(r >> 16);
}

static __device__ __forceinline__ f32x4 vmax4(f32x4 a, f32x4 b){
  f32x4 r;
  r[0] = fmaxf(a[0], b[0]); r[1] = fmaxf(a[1], b[1]);
  r[2] = fmaxf(a[2], b[2]); r[3] = fmaxf(a[3], b[3]);
  return r;
}

// async global->LDS DMA, 16B per lane; LDS dest = uniform base + lane*16
static __device__ __forceinline__ void gload_lds16(const void* g, void* l){
  __builtin_amdgcn_global_load_lds(
      (const __attribute__((address_space(1))) unsigned int*)g,
      (__attribute__((address_space(3))) unsigned int*)l, 16, 0, 0);
}

// ---------------- fused GroupNorm (blocks 0..255) + weight cvt (256..511) ----
// gn: x (B,C,H,W) fp32 -> hT (B x HW x C) bf16, float4-vectorized loads.
// cvt: w_qkv + w_proj fp32 -> bf16 (treated as one concatenated array).
__global__ __launch_bounds__(256) void gncvt_kernel(
    const float* __restrict__ x,
    const float* __restrict__ gamma, const float* __restrict__ beta,
    unsigned short* __restrict__ hT,
    const float* __restrict__ wa, const float* __restrict__ wb,
    unsigned short* __restrict__ oa, unsigned short* __restrict__ ob,
    int na, int nb)
{
  int bid = blockIdx.x;
  int t   = threadIdx.x;
  if (bid >= BATCH * NGRP){
    // ---- cvt part: 256 blocks x 256 thr x 4 float4 = na+nb elems
    int cb = bid - BATCH * NGRP;
    #pragma unroll
    for (int it = 0; it < 4; ++it){
      int i = (cb * 1024 + it * 256 + t) * 4;
      const float* src; unsigned short* dst; int j;
      if (i < na){ src = wa; dst = oa; j = i; }
      else { j = i - na; if (j >= nb) return; src = wb; dst = ob; }
      float4 v = *(const float4*)(src + j);
      ushort4 o;
      o.x = f2bf(v.x); o.y = f2bf(v.y); o.z = f2bf(v.z); o.w = f2bf(v.w);
      *(ushort4*)(dst + j) = o;
    }
    return;
  }
  // ---- gn part
  int b   = bid >> 5;   // / NGRP
  int grp = bid & 31;
  int c0  = grp * CPG;
  const float* xp = x + ((size_t)b * CDIM + c0) * HWD;
  f32x4 vals[CPG];           // thread t covers hw = t*4 .. t*4+3, 16 channels
  float s = 0.f, s2 = 0.f;
  #pragma unroll
  for (int j = 0; j < CPG; ++j){
    f32x4 v = *(const f32x4*)(xp + j * HWD + t * 4);
    vals[j] = v;
    #pragma unroll
    for (int k = 0; k < 4; ++k){ s += v[k]; s2 += v[k] * v[k]; }
  }
  #pragma unroll
  for (int off = 32; off > 0; off >>= 1){
    s  += __shfl_down(s, off);
    s2 += __shfl_down(s2, off);
  }
  __shared__ float red[8];
  __shared__ float stats[2];
  int lane = t & 63, wid = t >> 6;
  if (lane == 0){ red[wid] = s; red[wid + 4] = s2; }
  __syncthreads();
  if (t == 0){
    float ts  = red[0] + red[1] + red[2] + red[3];
    float ts2 = red[4] + red[5] + red[6] + red[7];
    float mean = ts * (1.f / (CPG * HWD));
    float var  = ts2 * (1.f / (CPG * HWD)) - mean * mean;
    stats[0] = mean; stats[1] = rsqrtf(var + EPSV);
  }
  __syncthreads();
  float mean = stats[0], inv = stats[1];
  float gm[CPG], bt[CPG];
  #pragma unroll
  for (int j = 0; j < CPG; ++j){ gm[j] = gamma[c0 + j] * inv; bt[j] = beta[c0 + j]; }
  #pragma unroll
  for (int k = 0; k < 4; ++k){
    unsigned pk[8];
    #pragma unroll
    for (int j = 0; j < 8; ++j){
      unsigned short lo = f2bf((vals[2*j][k]   - mean) * gm[2*j]   + bt[2*j]);
      unsigned short hi = f2bf((vals[2*j+1][k] - mean) * gm[2*j+1] + bt[2*j+1]);
      pk[j] = (unsigned)lo | ((unsigned)hi << 16);
    }
    size_t base = ((size_t)b * HWD + t * 4 + k) * CDIM + c0;
    uint4 a0 = {pk[0], pk[1], pk[2], pk[3]};
    uint4 a1 = {pk[4], pk[5], pk[6], pk[7]};
    *(uint4*)(hT + base)     = a0;
    *(uint4*)(hT + base + 8) = a1;
  }
}

// ---------------- GEMM: C = A(MxK) * BT(NxK)^T, per-batch B ----------------
// BK=64, global_load_lds staging (pre-swizzled source, swizzled b128 reads).
// MODE 0: QKV epilogue; MODE 1: proj epilogue (bias + residual, fp32 out)
template<int MODE>
__global__ __launch_bounds__(256) void gemm_bt(
    const unsigned short* __restrict__ A,
    const unsigned short* __restrict__ BT,
    const float* __restrict__ bias,
    const float* __restrict__ xres,
    float* __restrict__ outf,
    unsigned short* __restrict__ qT,
    unsigned short* __restrict__ kT,
    unsigned short* __restrict__ vb,
    int M, int N, int K)
{
  __shared__ unsigned short As[128*64];   // 16KB, rows of 128B, seg^=(row&7)
  __shared__ unsigned short Bs[128*64];
  int n0 = blockIdx.x * 128;
  int m0 = blockIdx.y * 128;
  int b  = blockIdx.z;
  int t  = threadIdx.x;
  int lane = t & 63, wid = t >> 6;
  int wr = wid >> 1, wc = wid & 1;
  int lr = lane & 15, g = lane >> 4;
  const unsigned short* Bb = BT + (size_t)b * N * K;

  // staging: wave wid covers rows [wid*32, wid*32+32), instr j: 8 rows,
  // lane: row = j*8 + (lane>>3), stored seg = lane&7 -> logical seg ^ (row&7)
  int srow = wid * 32 + (lane >> 3);
  int sseg = (lane & 7) ^ (lane >> 3);
  const unsigned short* ag = A  + (size_t)(m0 + srow) * K + sseg * 8;
  const unsigned short* bg = Bb + (size_t)(n0 + srow) * K + sseg * 8;

  f32x4 acc[4][4];
  f32x4 zz = {0.f, 0.f, 0.f, 0.f};
  #pragma unroll
  for (int m = 0; m < 4; ++m)
    #pragma unroll
    for (int n = 0; n < 4; ++n) acc[m][n] = zz;

  for (int k0 = 0; k0 < K; k0 += 64){
    #pragma unroll
    for (int j = 0; j < 4; ++j){
      gload_lds16(ag + (size_t)j*8*K + k0, &As[(wid*32 + j*8)*64]);
      gload_lds16(bg + (size_t)j*8*K + k0, &Bs[(wid*32 + j*8)*64]);
    }
    __syncthreads();   // drains vmcnt -> staged data visible
    #pragma unroll
    for (int kk = 0; kk < 2; ++kk){
      unsigned segx = (unsigned)(((kk*4 + g) ^ (lr & 7)) << 4);
      bf16x8 af[4], bfr[4];
      #pragma unroll
      for (int m = 0; m < 4; ++m)
        af[m] = *(const bf16x8*)((const char*)As + (unsigned)((wr*64 + m*16 + lr)*128) + segx);
      #pragma unroll
      for (int n = 0; n < 4; ++n)
        bfr[n] = *(const bf16x8*)((const char*)Bs + (unsigned)((wc*64 + n*16 + lr)*128) + segx);
      #pragma unroll
      for (int m = 0; m < 4; ++m)
        #pragma unroll
        for (int n = 0; n < 4; ++n)
          acc[m][n] = __builtin_amdgcn_mfma_f32_16x16x32_bf16(af[m], bfr[n], acc[m][n], 0, 0, 0);
    }
    __syncthreads();   // LDS free before next stage
  }

  if (MODE == 0){
    #pragma unroll
    for (int m = 0; m < 4; ++m){
      int o_base = m0 + wr*64 + m*16 + g*4;     // first of 4 consecutive o rows
      int s = o_base >> 9;
      int h = (o_base >> 6) & 7;
      int dbase = o_base & 63;
      float bv[4];
      #pragma unroll
      for (int r = 0; r < 4; ++r) bv[r] = bias[o_base + r];
      #pragma unroll
      for (int n = 0; n < 4; ++n){
        int hw = n0 + wc*64 + n*16 + lr;
        if (s == 2){
          // V: store d-major, k permuted within 32-blocks so flash PV
          // fragments (virtual slot g*8+j <-> actual k = 4g+(j&3)+16*(j>>2))
          // are contiguous b128 loads.
          int a = hw & 31;
          int hwp = (hw & ~31) | (((a >> 2) & 3) * 8 + (a & 3) + (((a >> 4) & 1) << 2));
          #pragma unroll
          for (int r = 0; r < 4; ++r){
            float val = acc[m][n][r] + bv[r];
            vb[(((size_t)b*NHEAD + h)*HD + dbase + r)*HWD + hwp] = f2bf(val);
          }
        } else {
          // q scaled by 0.125*log2(e) so attn softmax uses raw v_exp (2^x)
          float sc = (s == 0) ? QSC_L2E : 1.f;
          ushort4 pk;
          pk.x = f2bf((acc[m][n][0] + bv[0]) * sc);
          pk.y = f2bf((acc[m][n][1] + bv[1]) * sc);
          pk.z = f2bf((acc[m][n][2] + bv[2]) * sc);
          pk.w = f2bf((acc[m][n][3] + bv[3]) * sc);
          unsigned short* dst = (s == 0) ? qT : kT;
          *(ushort4*)&dst[(((size_t)b*NHEAD + h)*HWD + hw)*HD + dbase] = pk;
        }
      }
    }
  } else {
    #pragma unroll
    for (int m = 0; m < 4; ++m){
      int o0 = m0 + wr*64 + m*16 + g*4;
      #pragma unroll
      for (int n = 0; n < 4; ++n){
        int hw = n0 + wc*64 + n*16 + lr;
        #pragma unroll
        for (int r = 0; r < 4; ++r){
          int o = o0 + r;
          size_t idx = ((size_t)b * M + o) * N + hw;
          outf[idx] = acc[m][n][r] + bias[o] + xres[idx];
        }
      }
    }
  }
}

// ---------------- flash attention: 8 waves x 32q, XCD-local dispatch --------
// grid = (bh=64, qtile=4): XCD = bh % 8 -> all blocks sharing one bh's K/V
// land on ONE XCD; K/V stays L2-resident, fetched from HBM once.
// S' = K*Q^T via mfma(Kfrag, Qfrag): lane holds S'[k=4g+r+16t][q=lane&15].
// PV operand-SWAPPED: O' = mfma(A=V, B=P) -> O[col=q=lane&15][row=d=4g+r]:
// softmax state (m,l,f) is indexed by q=lane&15, so rescale / 1/l are pure
// per-lane scalar multiplies (no cross-lane shuffles), and the O-store is a
// coalesced ushort4 along d. P fed as produced (permuted-k trick; V stored
// with matching k-permutation). K/V chunks DMA'd via global_load_lds into
// the idle buffer while the current chunk computes.
// Softmax exp path: q pre-scaled by log2(e), exponential = raw v_exp_f32
// via __builtin_amdgcn_exp2f (r18: -1.05us vs __expf; libm exp2f is +8us).
// Max/sum use tree/vector shapes to cut serial dependency chains (r19 test).
__global__ __launch_bounds__(512, 2) void attn_flash(
    const unsigned short* __restrict__ qT,
    const unsigned short* __restrict__ kT,
    const unsigned short* __restrict__ vperm,
    unsigned short* __restrict__ aoT)
{
  __shared__ char smem[65536];   // 2 bufs x (16KB K + 16KB V)
  int bh = blockIdx.x;           // XCD = bh % 8 (round-robin dispatch)
  int b = bh >> 3, h = bh & 7;
  int t = threadIdx.x;
  int lane = t & 63, wid = t >> 6;   // 8 waves
  int lr = lane & 15, g = lane >> 4;
  int q0 = blockIdx.y * 256 + wid * 32;

  const unsigned short* qp = qT + ((size_t)bh * HWD + q0) * HD;
  const unsigned short* kp = kT + (size_t)bh * HWD * HD;
  const unsigned short* vp = vperm + (size_t)bh * HD * HWD;

  // staging geometry (per wave, 2 gload_lds each for K and V per chunk):
  // K: 128 rows x 128B; wave rows [wid*16, wid*16+16), instr j: 8 rows
  int krl  = lane >> 3;                       // 0..7
  int kseg = (lane & 7) ^ krl;                // pre-swizzled source seg (row&7==krl)
  const unsigned short* kg = kp + (size_t)(wid*16 + krl) * HD + kseg * 8;
  unsigned kdst = (unsigned)(wid * 16 * 128);
  // V: 64 rows x 256B; wave rows [wid*8, wid*8+8), instr j: 4 rows
  int vrl = lane >> 4;                        // 0..3

  // Q operand fragments: yq[qt][ks], q = qt*16 + lane&15 (q pre-scaled)
  bf16x8 yq[2][2];
  #pragma unroll
  for (int qt = 0; qt < 2; ++qt){
    yq[qt][0] = *(const bf16x8*)&qp[(qt*16 + lr)*HD + g*8];
    yq[qt][1] = *(const bf16x8*)&qp[(qt*16 + lr)*HD + 32 + g*8];
  }

  f32x4 accO[2][4];
  f32x4 zz = {0.f, 0.f, 0.f, 0.f};
  #pragma unroll
  for (int qt = 0; qt < 2; ++qt)
    #pragma unroll
    for (int dt = 0; dt < 4; ++dt) accO[qt][dt] = zz;
  float mrun[2] = {-1e30f, -1e30f};
  float lrun[2] = {0.f, 0.f};

  // prologue: stage chunk 0 into buf 0
  #pragma unroll
  for (int j = 0; j < 2; ++j){
    gload_lds16(kg + (size_t)j*8*HD, smem + kdst + j*8*128);
    int vrow = wid*8 + j*4 + vrl;
    int vseg = (lane & 15) ^ (vrow & 15);
    gload_lds16(vp + (size_t)vrow*HWD + vseg*8,
                smem + 16384u + (unsigned)vrow*256u);
  }
  __syncthreads();

  unsigned cur = 0;
  for (int kc = 0; kc < 8; ++kc){
    // async-stage next chunk into the idle buffer
    if (kc < 7){
      char* bufn = smem + (cur^1u)*32768u;
      int c1 = kc + 1;
      #pragma unroll
      for (int j = 0; j < 2; ++j){
        gload_lds16(kg + ((size_t)c1*128 + j*8)*HD, bufn + kdst + j*8*128);
        int vrow = wid*8 + j*4 + vrl;
        int vseg = (lane & 15) ^ (vrow & 15);
        gload_lds16(vp + (size_t)vrow*HWD + c1*128 + vseg*8,
                    bufn + 16384u + (unsigned)vrow*256u);
      }
    }

    char* kbuf = smem + cur*32768u;
    char* vbuf = kbuf + 16384;

    // QK^T: 8 k-tiles x 2 q-tiles; each K fragment pair feeds 2 q-tiles
    f32x4 s[2][8];
    __builtin_amdgcn_s_setprio(1);
    #pragma unroll
    for (int tt = 0; tt < 8; ++tt){
      unsigned rb = (unsigned)((tt*16 + lr) * 128);
      bf16x8 k0 = *(const bf16x8*)(kbuf + rb + (((g    ) ^ (lr&7)) << 4));
      bf16x8 k1 = *(const bf16x8*)(kbuf + rb + (((4 + g) ^ (lr&7)) << 4));
      #pragma unroll
      for (int qt = 0; qt < 2; ++qt){
        f32x4 z = zz;
        z = __builtin_amdgcn_mfma_f32_16x16x32_bf16(k0, yq[qt][0], z, 0, 0, 0);
        s[qt][tt] = __builtin_amdgcn_mfma_f32_16x16x32_bf16(k1, yq[qt][1], z, 0, 0, 0);
      }
    }
    __builtin_amdgcn_s_setprio(0);

    // online softmax per q-tile (tree max, vector sum, raw v_exp); per-lane
    #pragma unroll
    for (int qt = 0; qt < 2; ++qt){
      f32x4 vm = vmax4(vmax4(vmax4(s[qt][0], s[qt][1]), vmax4(s[qt][2], s[qt][3])),
                       vmax4(vmax4(s[qt][4], s[qt][5]), vmax4(s[qt][6], s[qt][7])));
      float cm = fmaxf(fmaxf(vm[0], vm[1]), fmaxf(vm[2], vm[3]));
      cm = fmaxf(cm, __shfl_xor(cm, 16));
      cm = fmaxf(cm, __shfl_xor(cm, 32));

      float mn = fmaxf(mrun[qt], cm);
      float f  = __builtin_amdgcn_exp2f(mrun[qt] - mn);   // first chunk: 2^-huge = 0
      mrun[qt] = mn;

      f32x4 vps = zz;
      #pragma unroll
      for (int tt = 0; tt < 8; ++tt){
        f32x4 e;
        #pragma unroll
        for (int r = 0; r < 4; ++r) e[r] = __builtin_amdgcn_exp2f(s[qt][tt][r] - mn);
        s[qt][tt] = e;
        vps += e;
      }
      float ps = (vps[0] + vps[1]) + (vps[2] + vps[3]);
      ps += __shfl_xor(ps, 16);
      ps += __shfl_xor(ps, 32);
      lrun[qt] = lrun[qt] * f + ps;

      // O rescale: accO col = q = lane&15 -> plain per-lane multiply
      #pragma unroll
      for (int dt = 0; dt < 4; ++dt)
        #pragma unroll
        for (int r = 0; r < 4; ++r) accO[qt][dt][r] *= f;
    }

    // PV (swapped): A = V (rows = d), B = P (cols = q, produced layout);
    // V pre-permuted to match P's k-slot order. Each V fragment feeds both
    // q-tiles.
    __builtin_amdgcn_s_setprio(1);
    #pragma unroll
    for (int mi = 0; mi < 4; ++mi){
      bf16x8 xp[2];
      #pragma unroll
      for (int qt = 0; qt < 2; ++qt)
        #pragma unroll
        for (int j = 0; j < 4; ++j){
          xp[qt][j]     = (__bf16)s[qt][2*mi][j];
          xp[qt][4 + j] = (__bf16)s[qt][2*mi + 1][j];
        }
      #pragma unroll
      for (int dt = 0; dt < 4; ++dt){
        unsigned rb = (unsigned)((dt*16 + lr) * 256) + (unsigned)((((mi*4 + g) ^ lr) & 15) << 4);
        bf16x8 yv = *(const bf16x8*)(vbuf + rb);
        #pragma unroll
        for (int qt = 0; qt < 2; ++qt)
          accO[qt][dt] = __builtin_amdgcn_mfma_f32_16x16x32_bf16(yv, xp[qt], accO[qt][dt], 0, 0, 0);
      }
    }
    __builtin_amdgcn_s_setprio(0);

    __syncthreads();   // drains vmcnt: next chunk staged + this chunk done
    cur ^= 1u;
  }

  // epilogue: lane holds O[d = dt*16+4g+r][q = q0+qt*16+lr]; normalize by
  // per-lane 1/l and store ushort4 along d (coalesced).
  #pragma unroll
  for (int qt = 0; qt < 2; ++qt){
    float invl = 1.f / lrun[qt];
    size_t rowb = ((size_t)b * HWD + q0 + qt*16 + lr) * CDIM + h*HD;
    #pragma unroll
    for (int dt = 0; dt < 4; ++dt){
      ushort4 pk;
      pk.x = f2bf(accO[qt][dt][0] * invl);
      pk.y = f2bf(accO[qt][dt][1] * invl);
      pk.z = f2bf(accO[qt][dt][2] * invl);
      pk.w = f2bf(accO[qt][dt][3] * invl);
      *(ushort4*)&aoT[rowb + dt*16 + g*4] = pk;
    }
  }
}

extern "C" void kernel_launch(void* const* d_in, const int* in_sizes, int n_in,
                              void* d_out, int out_size, void* d_ws, size_t ws_size,
                              hipStream_t stream) {
  const float* x      = (const float*)d_in[0];
  const float* gamma  = (const float*)d_in[1];
  const float* beta   = (const float*)d_in[2];
  const float* w_qkv  = (const float*)d_in[3];
  const float* b_qkv  = (const float*)d_in[4];
  const float* w_proj = (const float*)d_in[5];
  const float* b_proj = (const float*)d_in[6];
  float* out = (float*)d_out;

  char* ws = (char*)d_ws;
  size_t off = 0;
  unsigned short* wqkv_b  = (unsigned short*)(ws + off); off += (size_t)1536*512*2;   // 1.5 MB
  unsigned short* wproj_b = (unsigned short*)(ws + off); off += (size_t)512*512*2;    // 0.5 MB
  unsigned short* hT      = (unsigned short*)(ws + off); off += (size_t)BATCH*HWD*CDIM*2; // 8 MB
  unsigned short* qT      = (unsigned short*)(ws + off); off += (size_t)BATCH*NHEAD*HWD*HD*2;
  unsigned short* kT      = (unsigned short*)(ws + off); off += (size_t)BATCH*NHEAD*HWD*HD*2;
  unsigned short* vb      = (unsigned short*)(ws + off); off += (size_t)BATCH*NHEAD*HWD*HD*2;
  unsigned short* aoT     = hT;  // reuse: hT dead after QKV GEMM

  // 1. fused groupnorm + weight conversion
  gncvt_kernel<<<512, 256, 0, stream>>>(x, gamma, beta, hT,
      w_qkv, w_proj, wqkv_b, wproj_b, 1536*512, 512*512);

  // 2. QKV GEMM: (1536x512) x hT^T -> q/k/v
  gemm_bt<0><<<dim3(HWD/128, 1536/128, BATCH), 256, 0, stream>>>(
      wqkv_b, hT, b_qkv, nullptr, nullptr, qT, kT, vb, 1536, HWD, CDIM);

  // 3. flash attention (XCD-local: bh fastest in dispatch order)
  attn_flash<<<dim3(BATCH*NHEAD, HWD/256), 512, 0, stream>>>(qT, kT, vb, aoT);

  // 4. proj GEMM + bias + residual -> out (fp32)
  gemm_bt<1><<<dim3(HWD/128, CDIM/128, BATCH), 256, 0, stream>>>(
      wproj_b, aoT, b_proj, x, out, nullptr, nullptr, nullptr, CDIM, HWD, CDIM);
}

// Round 20
// 79.354 us; speedup vs baseline: 1.0217x; 1.0217x over previous
//
#include <hip/hip_runtime.h>
#include <stdint.h>
#include <math.h>

#define CDIM 512
#define NHEAD 8
#define HD 64
#define HWD 1024
#define BATCH 8
#define NGRP 32
#define CPG 16
#define EPSV 1e-5f
// q scale folded with log2(e): attn softmax uses raw v_exp_f32 (2^x) directly
#define QSC_L2E (0.125f * 1.44269504088896340736f)

typedef __bf16 bf16x8 __attribute__((ext_vector_type(8)));
typedef float f32x4 __attribute__((ext_vector_type(4)));

static __device__ __forceinline__ unsigned short f2bf(float x){
  union { float f; unsigned u; } v; v.f = x;
  unsigned r = v.u + 0x7fffu + ((v.u >> 16) & 1u);
  return (unsigned short)(r >> 16);
}

// async global->LDS DMA, 16B per lane; LDS dest = uniform base + lane*16
static __device__ __forceinline__ void gload_lds16(const void* g, void* l){
  __builtin_amdgcn_global_load_lds(
      (const __attribute__((address_space(1))) unsigned int*)g,
      (__attribute__((address_space(3))) unsigned int*)l, 16, 0, 0);
}

// ---------------- fused GroupNorm (blocks 0..255) + weight cvt (256..511) ----
// gn: x (B,C,H,W) fp32 -> hT (B x HW x C) bf16, float4-vectorized loads.
// cvt: w_qkv + w_proj fp32 -> bf16 (treated as one concatenated array).
__global__ __launch_bounds__(256) void gncvt_kernel(
    const float* __restrict__ x,
    const float* __restrict__ gamma, const float* __restrict__ beta,
    unsigned short* __restrict__ hT,
    const float* __restrict__ wa, const float* __restrict__ wb,
    unsigned short* __restrict__ oa, unsigned short* __restrict__ ob,
    int na, int nb)
{
  int bid = blockIdx.x;
  int t   = threadIdx.x;
  if (bid >= BATCH * NGRP){
    // ---- cvt part: 256 blocks x 256 thr x 4 float4 = na+nb elems
    int cb = bid - BATCH * NGRP;
    #pragma unroll
    for (int it = 0; it < 4; ++it){
      int i = (cb * 1024 + it * 256 + t) * 4;
      const float* src; unsigned short* dst; int j;
      if (i < na){ src = wa; dst = oa; j = i; }
      else { j = i - na; if (j >= nb) return; src = wb; dst = ob; }
      float4 v = *(const float4*)(src + j);
      ushort4 o;
      o.x = f2bf(v.x); o.y = f2bf(v.y); o.z = f2bf(v.z); o.w = f2bf(v.w);
      *(ushort4*)(dst + j) = o;
    }
    return;
  }
  // ---- gn part
  int b   = bid >> 5;   // / NGRP
  int grp = bid & 31;
  int c0  = grp * CPG;
  const float* xp = x + ((size_t)b * CDIM + c0) * HWD;
  f32x4 vals[CPG];           // thread t covers hw = t*4 .. t*4+3, 16 channels
  float s = 0.f, s2 = 0.f;
  #pragma unroll
  for (int j = 0; j < CPG; ++j){
    f32x4 v = *(const f32x4*)(xp + j * HWD + t * 4);
    vals[j] = v;
    #pragma unroll
    for (int k = 0; k < 4; ++k){ s += v[k]; s2 += v[k] * v[k]; }
  }
  #pragma unroll
  for (int off = 32; off > 0; off >>= 1){
    s  += __shfl_down(s, off);
    s2 += __shfl_down(s2, off);
  }
  __shared__ float red[8];
  __shared__ float stats[2];
  int lane = t & 63, wid = t >> 6;
  if (lane == 0){ red[wid] = s; red[wid + 4] = s2; }
  __syncthreads();
  if (t == 0){
    float ts  = red[0] + red[1] + red[2] + red[3];
    float ts2 = red[4] + red[5] + red[6] + red[7];
    float mean = ts * (1.f / (CPG * HWD));
    float var  = ts2 * (1.f / (CPG * HWD)) - mean * mean;
    stats[0] = mean; stats[1] = rsqrtf(var + EPSV);
  }
  __syncthreads();
  float mean = stats[0], inv = stats[1];
  float gm[CPG], bt[CPG];
  #pragma unroll
  for (int j = 0; j < CPG; ++j){ gm[j] = gamma[c0 + j] * inv; bt[j] = beta[c0 + j]; }
  #pragma unroll
  for (int k = 0; k < 4; ++k){
    unsigned pk[8];
    #pragma unroll
    for (int j = 0; j < 8; ++j){
      unsigned short lo = f2bf((vals[2*j][k]   - mean) * gm[2*j]   + bt[2*j]);
      unsigned short hi = f2bf((vals[2*j+1][k] - mean) * gm[2*j+1] + bt[2*j+1]);
      pk[j] = (unsigned)lo | ((unsigned)hi << 16);
    }
    size_t base = ((size_t)b * HWD + t * 4 + k) * CDIM + c0;
    uint4 a0 = {pk[0], pk[1], pk[2], pk[3]};
    uint4 a1 = {pk[4], pk[5], pk[6], pk[7]};
    *(uint4*)(hT + base)     = a0;
    *(uint4*)(hT + base + 8) = a1;
  }
}

// ---------------- GEMM: C = A(MxK) * BT(NxK)^T, per-batch B ----------------
// BK=64, global_load_lds staging (pre-swizzled source, swizzled b128 reads).
// MODE 0: QKV epilogue; MODE 1: proj epilogue (bias + residual, fp32 out)
template<int MODE>
__global__ __launch_bounds__(256) void gemm_bt(
    const unsigned short* __restrict__ A,
    const unsigned short* __restrict__ BT,
    const float* __restrict__ bias,
    const float* __restrict__ xres,
    float* __restrict__ outf,
    unsigned short* __restrict__ qT,
    unsigned short* __restrict__ kT,
    unsigned short* __restrict__ vb,
    int M, int N, int K)
{
  __shared__ unsigned short As[128*64];   // 16KB, rows of 128B, seg^=(row&7)
  __shared__ unsigned short Bs[128*64];
  int n0 = blockIdx.x * 128;
  int m0 = blockIdx.y * 128;
  int b  = blockIdx.z;
  int t  = threadIdx.x;
  int lane = t & 63, wid = t >> 6;
  int wr = wid >> 1, wc = wid & 1;
  int lr = lane & 15, g = lane >> 4;
  const unsigned short* Bb = BT + (size_t)b * N * K;

  // staging: wave wid covers rows [wid*32, wid*32+32), instr j: 8 rows,
  // lane: row = j*8 + (lane>>3), stored seg = lane&7 -> logical seg ^ (row&7)
  int srow = wid * 32 + (lane >> 3);
  int sseg = (lane & 7) ^ (lane >> 3);
  const unsigned short* ag = A  + (size_t)(m0 + srow) * K + sseg * 8;
  const unsigned short* bg = Bb + (size_t)(n0 + srow) * K + sseg * 8;

  f32x4 acc[4][4];
  f32x4 zz = {0.f, 0.f, 0.f, 0.f};
  #pragma unroll
  for (int m = 0; m < 4; ++m)
    #pragma unroll
    for (int n = 0; n < 4; ++n) acc[m][n] = zz;

  for (int k0 = 0; k0 < K; k0 += 64){
    #pragma unroll
    for (int j = 0; j < 4; ++j){
      gload_lds16(ag + (size_t)j*8*K + k0, &As[(wid*32 + j*8)*64]);
      gload_lds16(bg + (size_t)j*8*K + k0, &Bs[(wid*32 + j*8)*64]);
    }
    __syncthreads();   // drains vmcnt -> staged data visible
    #pragma unroll
    for (int kk = 0; kk < 2; ++kk){
      unsigned segx = (unsigned)(((kk*4 + g) ^ (lr & 7)) << 4);
      bf16x8 af[4], bfr[4];
      #pragma unroll
      for (int m = 0; m < 4; ++m)
        af[m] = *(const bf16x8*)((const char*)As + (unsigned)((wr*64 + m*16 + lr)*128) + segx);
      #pragma unroll
      for (int n = 0; n < 4; ++n)
        bfr[n] = *(const bf16x8*)((const char*)Bs + (unsigned)((wc*64 + n*16 + lr)*128) + segx);
      #pragma unroll
      for (int m = 0; m < 4; ++m)
        #pragma unroll
        for (int n = 0; n < 4; ++n)
          acc[m][n] = __builtin_amdgcn_mfma_f32_16x16x32_bf16(af[m], bfr[n], acc[m][n], 0, 0, 0);
    }
    __syncthreads();   // LDS free before next stage
  }

  if (MODE == 0){
    #pragma unroll
    for (int m = 0; m < 4; ++m){
      int o_base = m0 + wr*64 + m*16 + g*4;     // first of 4 consecutive o rows
      int s = o_base >> 9;
      int h = (o_base >> 6) & 7;
      int dbase = o_base & 63;
      float bv[4];
      #pragma unroll
      for (int r = 0; r < 4; ++r) bv[r] = bias[o_base + r];
      #pragma unroll
      for (int n = 0; n < 4; ++n){
        int hw = n0 + wc*64 + n*16 + lr;
        if (s == 2){
          // V: store d-major, k permuted within 32-blocks so flash PV
          // fragments (virtual slot g*8+j <-> actual k = 4g+(j&3)+16*(j>>2))
          // are contiguous b128 loads.
          int a = hw & 31;
          int hwp = (hw & ~31) | (((a >> 2) & 3) * 8 + (a & 3) + (((a >> 4) & 1) << 2));
          #pragma unroll
          for (int r = 0; r < 4; ++r){
            float val = acc[m][n][r] + bv[r];
            vb[(((size_t)b*NHEAD + h)*HD + dbase + r)*HWD + hwp] = f2bf(val);
          }
        } else {
          // q scaled by 0.125*log2(e) so attn softmax uses raw v_exp (2^x)
          float sc = (s == 0) ? QSC_L2E : 1.f;
          ushort4 pk;
          pk.x = f2bf((acc[m][n][0] + bv[0]) * sc);
          pk.y = f2bf((acc[m][n][1] + bv[1]) * sc);
          pk.z = f2bf((acc[m][n][2] + bv[2]) * sc);
          pk.w = f2bf((acc[m][n][3] + bv[3]) * sc);
          unsigned short* dst = (s == 0) ? qT : kT;
          *(ushort4*)&dst[(((size_t)b*NHEAD + h)*HWD + hw)*HD + dbase] = pk;
        }
      }
    }
  } else {
    #pragma unroll
    for (int m = 0; m < 4; ++m){
      int o0 = m0 + wr*64 + m*16 + g*4;
      #pragma unroll
      for (int n = 0; n < 4; ++n){
        int hw = n0 + wc*64 + n*16 + lr;
        #pragma unroll
        for (int r = 0; r < 4; ++r){
          int o = o0 + r;
          size_t idx = ((size_t)b * M + o) * N + hw;
          outf[idx] = acc[m][n][r] + bias[o] + xres[idx];
        }
      }
    }
  }
}

// ---------------- flash attention: 8 waves x 32q, XCD-local dispatch --------
// grid = (bh=64, qtile=4): XCD = bh % 8 -> all blocks sharing one bh's K/V
// land on ONE XCD; K/V stays L2-resident, fetched from HBM once.
// S' = K*Q^T via mfma(Kfrag, Qfrag): lane holds S'[k=4g+r+16t][q=lane&15].
// PV operand-SWAPPED: O' = mfma(A=V, B=P) -> O[col=q=lane&15][row=d=4g+r]:
// softmax state (m,l,f) is indexed by q=lane&15, so rescale / 1/l are pure
// per-lane scalar multiplies (no cross-lane shuffles), and the O-store is a
// coalesced ushort4 along d. P fed as produced (permuted-k trick; V stored
// with matching k-permutation). K/V chunks DMA'd via global_load_lds into
// the idle buffer while the current chunk computes.
// Softmax exp path: q pre-scaled by log2(e), exponential = raw v_exp_f32
// via __builtin_amdgcn_exp2f (r18: -1.05us vs __expf; libm exp2f +8us,
// tree-max/vector-sum +1.7us -- both measured and rejected).
__global__ __launch_bounds__(512, 2) void attn_flash(
    const unsigned short* __restrict__ qT,
    const unsigned short* __restrict__ kT,
    const unsigned short* __restrict__ vperm,
    unsigned short* __restrict__ aoT)
{
  __shared__ char smem[65536];   // 2 bufs x (16KB K + 16KB V)
  int bh = blockIdx.x;           // XCD = bh % 8 (round-robin dispatch)
  int b = bh >> 3, h = bh & 7;
  int t = threadIdx.x;
  int lane = t & 63, wid = t >> 6;   // 8 waves
  int lr = lane & 15, g = lane >> 4;
  int q0 = blockIdx.y * 256 + wid * 32;

  const unsigned short* qp = qT + ((size_t)bh * HWD + q0) * HD;
  const unsigned short* kp = kT + (size_t)bh * HWD * HD;
  const unsigned short* vp = vperm + (size_t)bh * HD * HWD;

  // staging geometry (per wave, 2 gload_lds each for K and V per chunk):
  // K: 128 rows x 128B; wave rows [wid*16, wid*16+16), instr j: 8 rows
  int krl  = lane >> 3;                       // 0..7
  int kseg = (lane & 7) ^ krl;                // pre-swizzled source seg (row&7==krl)
  const unsigned short* kg = kp + (size_t)(wid*16 + krl) * HD + kseg * 8;
  unsigned kdst = (unsigned)(wid * 16 * 128);
  // V: 64 rows x 256B; wave rows [wid*8, wid*8+8), instr j: 4 rows
  int vrl = lane >> 4;                        // 0..3

  // Q operand fragments: yq[qt][ks], q = qt*16 + lane&15 (q pre-scaled)
  bf16x8 yq[2][2];
  #pragma unroll
  for (int qt = 0; qt < 2; ++qt){
    yq[qt][0] = *(const bf16x8*)&qp[(qt*16 + lr)*HD + g*8];
    yq[qt][1] = *(const bf16x8*)&qp[(qt*16 + lr)*HD + 32 + g*8];
  }

  f32x4 accO[2][4];
  f32x4 zz = {0.f, 0.f, 0.f, 0.f};
  #pragma unroll
  for (int qt = 0; qt < 2; ++qt)
    #pragma unroll
    for (int dt = 0; dt < 4; ++dt) accO[qt][dt] = zz;
  float mrun[2] = {-1e30f, -1e30f};
  float lrun[2] = {0.f, 0.f};

  // prologue: stage chunk 0 into buf 0
  #pragma unroll
  for (int j = 0; j < 2; ++j){
    gload_lds16(kg + (size_t)j*8*HD, smem + kdst + j*8*128);
    int vrow = wid*8 + j*4 + vrl;
    int vseg = (lane & 15) ^ (vrow & 15);
    gload_lds16(vp + (size_t)vrow*HWD + vseg*8,
                smem + 16384u + (unsigned)vrow*256u);
  }
  __syncthreads();

  unsigned cur = 0;
  for (int kc = 0; kc < 8; ++kc){
    // async-stage next chunk into the idle buffer
    if (kc < 7){
      char* bufn = smem + (cur^1u)*32768u;
      int c1 = kc + 1;
      #pragma unroll
      for (int j = 0; j < 2; ++j){
        gload_lds16(kg + ((size_t)c1*128 + j*8)*HD, bufn + kdst + j*8*128);
        int vrow = wid*8 + j*4 + vrl;
        int vseg = (lane & 15) ^ (vrow & 15);
        gload_lds16(vp + (size_t)vrow*HWD + c1*128 + vseg*8,
                    bufn + 16384u + (unsigned)vrow*256u);
      }
    }

    char* kbuf = smem + cur*32768u;
    char* vbuf = kbuf + 16384;

    // QK^T: 8 k-tiles x 2 q-tiles; each K fragment pair feeds 2 q-tiles
    f32x4 s[2][8];
    __builtin_amdgcn_s_setprio(1);
    #pragma unroll
    for (int tt = 0; tt < 8; ++tt){
      unsigned rb = (unsigned)((tt*16 + lr) * 128);
      bf16x8 k0 = *(const bf16x8*)(kbuf + rb + (((g    ) ^ (lr&7)) << 4));
      bf16x8 k1 = *(const bf16x8*)(kbuf + rb + (((4 + g) ^ (lr&7)) << 4));
      #pragma unroll
      for (int qt = 0; qt < 2; ++qt){
        f32x4 z = zz;
        z = __builtin_amdgcn_mfma_f32_16x16x32_bf16(k0, yq[qt][0], z, 0, 0, 0);
        s[qt][tt] = __builtin_amdgcn_mfma_f32_16x16x32_bf16(k1, yq[qt][1], z, 0, 0, 0);
      }
    }
    __builtin_amdgcn_s_setprio(0);

    // online softmax per q-tile; all state indexed by q=lane&15 (per-lane)
    #pragma unroll
    for (int qt = 0; qt < 2; ++qt){
      float cm = -1e30f;
      #pragma unroll
      for (int tt = 0; tt < 8; ++tt)
        #pragma unroll
        for (int r = 0; r < 4; ++r) cm = fmaxf(cm, s[qt][tt][r]);
      cm = fmaxf(cm, __shfl_xor(cm, 16));
      cm = fmaxf(cm, __shfl_xor(cm, 32));

      float mn = fmaxf(mrun[qt], cm);
      float f  = __builtin_amdgcn_exp2f(mrun[qt] - mn);   // first chunk: 2^-huge = 0
      mrun[qt] = mn;

      float ps = 0.f;
      #pragma unroll
      for (int tt = 0; tt < 8; ++tt)
        #pragma unroll
        for (int r = 0; r < 4; ++r){
          float e = __builtin_amdgcn_exp2f(s[qt][tt][r] - mn);
          s[qt][tt][r] = e; ps += e;
        }
      ps += __shfl_xor(ps, 16);
      ps += __shfl_xor(ps, 32);
      lrun[qt] = lrun[qt] * f + ps;

      // O rescale: accO col = q = lane&15 -> plain per-lane multiply
      #pragma unroll
      for (int dt = 0; dt < 4; ++dt)
        #pragma unroll
        for (int r = 0; r < 4; ++r) accO[qt][dt][r] *= f;
    }

    // PV (swapped): A = V (rows = d), B = P (cols = q, produced layout);
    // V pre-permuted to match P's k-slot order. Each V fragment feeds both
    // q-tiles.
    __builtin_amdgcn_s_setprio(1);
    #pragma unroll
    for (int mi = 0; mi < 4; ++mi){
      bf16x8 xp[2];
      #pragma unroll
      for (int qt = 0; qt < 2; ++qt)
        #pragma unroll
        for (int j = 0; j < 4; ++j){
          xp[qt][j]     = (__bf16)s[qt][2*mi][j];
          xp[qt][4 + j] = (__bf16)s[qt][2*mi + 1][j];
        }
      #pragma unroll
      for (int dt = 0; dt < 4; ++dt){
        unsigned rb = (unsigned)((dt*16 + lr) * 256) + (unsigned)((((mi*4 + g) ^ lr) & 15) << 4);
        bf16x8 yv = *(const bf16x8*)(vbuf + rb);
        #pragma unroll
        for (int qt = 0; qt < 2; ++qt)
          accO[qt][dt] = __builtin_amdgcn_mfma_f32_16x16x32_bf16(yv, xp[qt], accO[qt][dt], 0, 0, 0);
      }
    }
    __builtin_amdgcn_s_setprio(0);

    __syncthreads();   // drains vmcnt: next chunk staged + this chunk done
    cur ^= 1u;
  }

  // epilogue: lane holds O[d = dt*16+4g+r][q = q0+qt*16+lr]; normalize by
  // per-lane 1/l and store ushort4 along d (coalesced).
  #pragma unroll
  for (int qt = 0; qt < 2; ++qt){
    float invl = 1.f / lrun[qt];
    size_t rowb = ((size_t)b * HWD + q0 + qt*16 + lr) * CDIM + h*HD;
    #pragma unroll
    for (int dt = 0; dt < 4; ++dt){
      ushort4 pk;
      pk.x = f2bf(accO[qt][dt][0] * invl);
      pk.y = f2bf(accO[qt][dt][1] * invl);
      pk.z = f2bf(accO[qt][dt][2] * invl);
      pk.w = f2bf(accO[qt][dt][3] * invl);
      *(ushort4*)&aoT[rowb + dt*16 + g*4] = pk;
    }
  }
}

extern "C" void kernel_launch(void* const* d_in, const int* in_sizes, int n_in,
                              void* d_out, int out_size, void* d_ws, size_t ws_size,
                              hipStream_t stream) {
  const float* x      = (const float*)d_in[0];
  const float* gamma  = (const float*)d_in[1];
  const float* beta   = (const float*)d_in[2];
  const float* w_qkv  = (const float*)d_in[3];
  const float* b_qkv  = (const float*)d_in[4];
  const float* w_proj = (const float*)d_in[5];
  const float* b_proj = (const float*)d_in[6];
  float* out = (float*)d_out;

  char* ws = (char*)d_ws;
  size_t off = 0;
  unsigned short* wqkv_b  = (unsigned short*)(ws + off); off += (size_t)1536*512*2;   // 1.5 MB
  unsigned short* wproj_b = (unsigned short*)(ws + off); off += (size_t)512*512*2;    // 0.5 MB
  unsigned short* hT      = (unsigned short*)(ws + off); off += (size_t)BATCH*HWD*CDIM*2; // 8 MB
  unsigned short* qT      = (unsigned short*)(ws + off); off += (size_t)BATCH*NHEAD*HWD*HD*2;
  unsigned short* kT      = (unsigned short*)(ws + off); off += (size_t)BATCH*NHEAD*HWD*HD*2;
  unsigned short* vb      = (unsigned short*)(ws + off); off += (size_t)BATCH*NHEAD*HWD*HD*2;
  unsigned short* aoT     = hT;  // reuse: hT dead after QKV GEMM

  // 1. fused groupnorm + weight conversion
  gncvt_kernel<<<512, 256, 0, stream>>>(x, gamma, beta, hT,
      w_qkv, w_proj, wqkv_b, wproj_b, 1536*512, 512*512);

  // 2. QKV GEMM: (1536x512) x hT^T -> q/k/v
  gemm_bt<0><<<dim3(HWD/128, 1536/128, BATCH), 256, 0, stream>>>(
      wqkv_b, hT, b_qkv, nullptr, nullptr, qT, kT, vb, 1536, HWD, CDIM);

  // 3. flash attention (XCD-local: bh fastest in dispatch order)
  attn_flash<<<dim3(BATCH*NHEAD, HWD/256), 512, 0, stream>>>(qT, kT, vb, aoT);

  // 4. proj GEMM + bias + residual -> out (fp32)
  gemm_bt<1><<<dim3(HWD/128, CDIM/128, BATCH), 256, 0, stream>>>(
      wproj_b, aoT, b_proj, x, out, nullptr, nullptr, nullptr, CDIM, HWD, CDIM);
}